// Round 2
// baseline (291.231 us; speedup 1.0000x reference)
//
#include <hip/hip_runtime.h>
#include <hip/hip_bf16.h>

#define NN_ 8192
#define DD_ 128
#define NCLS 512
#define NSPLIT 16
#define JSPLIT (NN_ / NSPLIT)  // 512

typedef short bf16x8 __attribute__((ext_vector_type(8)));
typedef float f32x4 __attribute__((ext_vector_type(4)));

union U4 { uint4 u; bf16x8 h; };

#if __has_builtin(__builtin_amdgcn_exp2f)
#define EXP2(x) __builtin_amdgcn_exp2f(x)
#else
#define EXP2(x) __expf((x) * 0.69314718056f)
#endif

#define C1 115.415603f  /* 80*log2(e) */
#define C2 96.9491065f  /* 67.2*log2(e) */
#define LN2 0.69314718056f

__device__ __forceinline__ unsigned short f2bf(float f) {
    unsigned int u = __float_as_uint(f);
    unsigned int r = (u + 0x7FFFu + ((u >> 16) & 1u)) >> 16;  // RNE
    return (unsigned short)r;
}

// Fragment-swizzled layout (uint4 units): fb[grp*256 + chunk*16 + row16]
//   grp = slot>>4, row16 = slot&15, chunk = 8-bf16 block (16B) in [0,16).
// MFMA frag load for K-block kc reads fb[grp*256 + kc*64 + lane].
// Rows stored label-sorted; same-label columns of any 16-row wave group are
// one contiguous range [lo, hi); tiles outside it use the 5-op negative path.

// ---------------- kernel 0: counting sort of rows by label ----------------------
// Produces srcrow[slot] = original row (inverse perm, for gather in k_norm),
// plab[slot] = sorted labels, start[c] = first slot of class c, start[NCLS]=NN.
__global__ __launch_bounds__(1024) void k_sort(const int* __restrict__ labels,
                                               int* __restrict__ srcrow,
                                               int* __restrict__ plab,
                                               int* __restrict__ start) {
    __shared__ int hist[NCLS];
    __shared__ int base[NCLS];
    __shared__ int wsum[8];
    int t = threadIdx.x;
    if (t < NCLS) hist[t] = 0;
    __syncthreads();
    int4 la = ((const int4*)labels)[t * 2];
    int4 lb = ((const int4*)labels)[t * 2 + 1];
    int l[8] = {la.x, la.y, la.z, la.w, lb.x, lb.y, lb.z, lb.w};
#pragma unroll
    for (int k = 0; k < 8; k++) atomicAdd(&hist[l[k]], 1);
    __syncthreads();
    int v = (t < NCLS) ? hist[t] : 0;
    int x = v;
#pragma unroll
    for (int m = 1; m < 64; m <<= 1) {
        int y = __shfl_up(x, m);
        if ((t & 63) >= m) x += y;
    }
    if (t < NCLS && (t & 63) == 63) wsum[t >> 6] = x;
    __syncthreads();
    if (t < NCLS) {
        int w = t >> 6, woff = 0;
#pragma unroll
        for (int k = 0; k < 8; k++)
            if (k < w) woff += wsum[k];
        int excl = woff + x - v;  // exclusive prefix over classes
        start[t] = excl;
        base[t] = excl;
        if (t == 0) start[NCLS] = NN_;
    }
    __syncthreads();
#pragma unroll
    for (int k = 0; k < 8; k++) {
        int p = atomicAdd(&base[l[k]], 1);
        srcrow[p] = t * 8 + k;
        plab[p] = l[k];
    }
}

// ---------------- kernel 1: L2-normalize rows -> bf16 (gather, coalesced store) -
__global__ __launch_bounds__(256) void k_norm(const float* __restrict__ x,
                                              const int* __restrict__ srcrow,
                                              unsigned short* __restrict__ ebf) {
    int t = threadIdx.x;
    int r16 = t >> 4;
    int g = t & 15;
    int slot = blockIdx.x * 16 + r16;
    int orig = srcrow[slot];  // 16 threads/row load same value (L1 broadcast)
    const float4* xr = (const float4*)(x + (size_t)orig * DD_);
    float4 v0 = xr[g * 2];
    float4 v1 = xr[g * 2 + 1];
    float ss = v0.x * v0.x + v0.y * v0.y + v0.z * v0.z + v0.w * v0.w +
               v1.x * v1.x + v1.y * v1.y + v1.z * v1.z + v1.w * v1.w;
#pragma unroll
    for (int m = 1; m < 16; m <<= 1) ss += __shfl_xor(ss, m);
    float inv = 1.0f / fmaxf(sqrtf(ss), 1e-12f);
    float vs[8] = {v0.x, v0.y, v0.z, v0.w, v1.x, v1.y, v1.z, v1.w};
    unsigned int p[4];
#pragma unroll
    for (int k = 0; k < 4; k++) {
        unsigned short lo = f2bf(vs[2 * k] * inv);
        unsigned short hi = f2bf(vs[2 * k + 1] * inv);
        p[k] = (unsigned int)lo | ((unsigned int)hi << 16);
    }
    uint4 out = {p[0], p[1], p[2], p[3]};
    ((uint4*)ebf)[blockIdx.x * 256 + g * 16 + r16] = out;  // coalesced swizzled store
}

// ---------------- kernel 2: main sim + masked LSE pass --------------------------
// grid (NSPLIT=16, 64) = 1024 blocks -> 4 blocks/CU, 32 waves/CU.
__global__ __launch_bounds__(512, 8) void k_main(const unsigned short* __restrict__ ebf,
                                                 const int* __restrict__ plab,
                                                 const int* __restrict__ start,
                                                 float* __restrict__ states) {
    const int lane = threadIdx.x & 63;
    const int wave = threadIdx.x >> 6;
    const int quad = lane >> 4;
    const int lcol = lane & 15;
    const int rowbase = blockIdx.y * 128 + wave * 16;
    const int jsplit = blockIdx.x;
    const int j0 = jsplit * JSPLIT;

    const uint4* fb = (const uint4*)ebf;

    U4 afr[4];
#pragma unroll
    for (int kc = 0; kc < 4; kc++) afr[kc].u = fb[(rowbase >> 4) * 256 + kc * 64 + lane];

    int il[4];
#pragma unroll
    for (int r = 0; r < 4; r++) il[r] = plab[rowbase + quad * 4 + r];

    // wave-uniform same-label column range [lo, hi)
    int labmin = __builtin_amdgcn_readfirstlane(plab[rowbase]);
    int labmax = __builtin_amdgcn_readfirstlane(plab[rowbase + 15]);
    int lo = __builtin_amdgcn_readfirstlane(start[labmin]);
    int hi = __builtin_amdgcn_readfirstlane(start[labmax + 1]);

    float S_an[4] = {0.f, 0.f, 0.f, 0.f};
    float m_p[4] = {-1e30f, -1e30f, -1e30f, -1e30f};  // log2 units
    float s_p[4] = {0.f, 0.f, 0.f, 0.f};
    float cnt[4] = {0.f, 0.f, 0.f, 0.f};  // same-label count (incl self)

    U4 b0[4], b1[4];
#pragma unroll
    for (int kc = 0; kc < 4; kc++) b0[kc].u = fb[(j0 >> 4) * 256 + kc * 64 + lane];
#pragma unroll
    for (int kc = 0; kc < 4; kc++) b1[kc].u = fb[((j0 + 16) >> 4) * 256 + kc * 64 + lane];

    const int NIT = JSPLIT / 32;
    for (int it = 0; it < NIT; ++it) {
        const int jt = j0 + it * 32;
        const int jp = (it + 1 < NIT) ? jt + 32 : j0;  // prefetch target (wrap ok)

        // ---- tile 0: columns jt..jt+15, fragments in b0 ----
        {
            f32x4 acc = {0.f, 0.f, 0.f, 0.f};
#pragma unroll
            for (int kc = 0; kc < 4; kc++)
                acc = __builtin_amdgcn_mfma_f32_16x16x32_bf16(afr[kc].h, b0[kc].h, acc, 0, 0, 0);
            // refill b0 now: load latency hides under the acc-dependent epilogue
#pragma unroll
            for (int kc = 0; kc < 4; kc++) b0[kc].u = fb[(jp >> 4) * 256 + kc * 64 + lane];
            if (jt < hi && jt + 16 > lo) {
                int jl = plab[jt + lcol];
                int j = jt + lcol;
#pragma unroll
                for (int r = 0; r < 4; r++) {
                    float s = acc[r];
                    int i = rowbase + quad * 4 + r;
                    bool same = (jl == il[r]);
                    float a = fmaxf(s + 0.4f, 0.0f);
                    float e = EXP2(fmaf(a * C1, s - 0.4f, -C2));
                    S_an[r] += same ? 0.0f : e;
                    cnt[r] += same ? 1.0f : 0.0f;
                    if (same && j != i) {
                        float al = fmaxf(1.4f - s, 0.0f) * (-C1);
                        float tp = al * (s - 0.6f);
                        float mn = fmaxf(m_p[r], tp);
                        s_p[r] = s_p[r] * EXP2(m_p[r] - mn) + EXP2(tp - mn);
                        m_p[r] = mn;
                    }
                }
            } else {
#pragma unroll
                for (int r = 0; r < 4; r++) {
                    float s = acc[r];
                    float a = fmaxf(s + 0.4f, 0.0f);
                    S_an[r] += EXP2(fmaf(a * C1, s - 0.4f, -C2));
                }
            }
        }

        // ---- tile 1: columns jt+16..jt+31, fragments in b1 ----
        {
            f32x4 acc = {0.f, 0.f, 0.f, 0.f};
#pragma unroll
            for (int kc = 0; kc < 4; kc++)
                acc = __builtin_amdgcn_mfma_f32_16x16x32_bf16(afr[kc].h, b1[kc].h, acc, 0, 0, 0);
#pragma unroll
            for (int kc = 0; kc < 4; kc++) b1[kc].u = fb[((jp + 16) >> 4) * 256 + kc * 64 + lane];
            const int jtt = jt + 16;
            if (jtt < hi && jtt + 16 > lo) {
                int jl = plab[jtt + lcol];
                int j = jtt + lcol;
#pragma unroll
                for (int r = 0; r < 4; r++) {
                    float s = acc[r];
                    int i = rowbase + quad * 4 + r;
                    bool same = (jl == il[r]);
                    float a = fmaxf(s + 0.4f, 0.0f);
                    float e = EXP2(fmaf(a * C1, s - 0.4f, -C2));
                    S_an[r] += same ? 0.0f : e;
                    cnt[r] += same ? 1.0f : 0.0f;
                    if (same && j != i) {
                        float al = fmaxf(1.4f - s, 0.0f) * (-C1);
                        float tp = al * (s - 0.6f);
                        float mn = fmaxf(m_p[r], tp);
                        s_p[r] = s_p[r] * EXP2(m_p[r] - mn) + EXP2(tp - mn);
                        m_p[r] = mn;
                    }
                }
            } else {
#pragma unroll
                for (int r = 0; r < 4; r++) {
                    float s = acc[r];
                    float a = fmaxf(s + 0.4f, 0.0f);
                    S_an[r] += EXP2(fmaf(a * C1, s - 0.4f, -C2));
                }
            }
        }
    }

#pragma unroll
    for (int r = 0; r < 4; r++) {
#pragma unroll
        for (int m = 1; m < 16; m <<= 1) {
            S_an[r] += __shfl_xor(S_an[r], m);
            cnt[r] += __shfl_xor(cnt[r], m);
            float m2 = __shfl_xor(m_p[r], m);
            float s2 = __shfl_xor(s_p[r], m);
            float mn = fmaxf(m_p[r], m2);
            s_p[r] = s_p[r] * EXP2(m_p[r] - mn) + s2 * EXP2(m2 - mn);
            m_p[r] = mn;
        }
    }
    if (lcol == 0) {
#pragma unroll
        for (int r = 0; r < 4; r++) {
            int i = rowbase + quad * 4 + r;
            float4 st = {m_p[r], s_p[r], S_an[r], cnt[r]};
            ((float4*)states)[(size_t)i * NSPLIT + jsplit] = st;
        }
    }
}

// ---------------- kernel 3: merge splits, per-row loss, per-wave partials -------
__global__ __launch_bounds__(256) void k_fin(const float* __restrict__ states,
                                             float* __restrict__ partials) {
    int i = blockIdx.x * 256 + threadIdx.x;
    float m_p = -1e30f, s_p = 0.f, S_an = 0.f, cnt = 0.f;
#pragma unroll
    for (int k = 0; k < NSPLIT; k++) {
        float4 st = ((const float4*)states)[(size_t)i * NSPLIT + k];
        S_an += st.z;
        cnt += st.w;
        float mn = fmaxf(m_p, st.x);
        s_p = s_p * EXP2(m_p - mn) + st.y * EXP2(st.x - mn);
        m_p = mn;
    }
    int np = (int)cnt - 1;
    int nn = NN_ - (int)cnt;
    float loss = 0.0f, v = 0.0f;
    if (np > 0 && nn > 0 && s_p > 0.f && S_an > 0.f) {
        float lse_p = LN2 * m_p + __logf(s_p);
        float lse_n = 67.2f + __logf(S_an);
        float z = lse_p + lse_n + __logf((float)np) + __logf((float)nn);
        loss = fmaxf(z, 0.0f) + log1pf(__expf(-fabsf(z)));  // stable softplus
        v = 1.0f;
    }
#pragma unroll
    for (int m = 1; m < 64; m <<= 1) {
        loss += __shfl_xor(loss, m);
        v += __shfl_xor(v, m);
    }
    if ((threadIdx.x & 63) == 0) {
        int w = (blockIdx.x << 2) | (threadIdx.x >> 6);
        partials[w * 2] = loss;
        partials[w * 2 + 1] = v;
    }
}

// ---------------- kernel 4: final reduce over 128 wave-partials -----------------
__global__ void k_div(const float* __restrict__ partials, float* __restrict__ out) {
    int t = threadIdx.x;  // 64 threads
    float loss = partials[t * 2] + partials[(t + 64) * 2];
    float v = partials[t * 2 + 1] + partials[(t + 64) * 2 + 1];
#pragma unroll
    for (int m = 1; m < 64; m <<= 1) {
        loss += __shfl_xor(loss, m);
        v += __shfl_xor(v, m);
    }
    if (t == 0) out[0] = loss / fmaxf(v, 1.0f);
}

// ---------------- launch --------------------------------------------------------
extern "C" void kernel_launch(void* const* d_in, const int* in_sizes, int n_in,
                              void* d_out, int out_size, void* d_ws, size_t ws_size,
                              hipStream_t stream) {
    const float* embeds = (const float*)d_in[0];
    const int* labels = (const int*)d_in[1];
    float* out = (float*)d_out;

    char* ws = (char*)d_ws;
    unsigned short* ebf = (unsigned short*)ws;  // 2,097,152 B
    float* states = (float*)(ws + 2097152);     // 8192*16*16 = 2,097,152 B
    float* partials = (float*)(ws + 4194304);   // 1,024 B
    int* srcrow = (int*)(ws + 4195328);         // 32,768 B
    int* plab = (int*)(ws + 4228096);           // 32,768 B
    int* start = (int*)(ws + 4260864);          // 2,052 B

    k_sort<<<1, 1024, 0, stream>>>(labels, srcrow, plab, start);
    k_norm<<<NN_ / 16, 256, 0, stream>>>(embeds, srcrow, ebf);
    k_main<<<dim3(NSPLIT, NN_ / 128), 512, 0, stream>>>(ebf, plab, start, states);
    k_fin<<<NN_ / 256, 256, 0, stream>>>(states, partials);
    k_div<<<1, 64, 0, stream>>>(partials, out);
}

// Round 4
// 112.015 us; speedup vs baseline: 2.5999x; 2.5999x over previous
//
#include <hip/hip_runtime.h>
#include <hip/hip_bf16.h>

#define NN_ 8192
#define DD_ 128
#define NCLS 512
#define NSPLIT 16
#define JSPLIT (NN_ / NSPLIT)  // 512

typedef short bf16x8 __attribute__((ext_vector_type(8)));
typedef float f32x4 __attribute__((ext_vector_type(4)));

union U4 { uint4 u; bf16x8 h; };

#if __has_builtin(__builtin_amdgcn_exp2f)
#define EXP2(x) __builtin_amdgcn_exp2f(x)
#else
#define EXP2(x) __expf((x) * 0.69314718056f)
#endif

#define C1 115.415603f  /* 80*log2(e) */
#define C2 96.9491065f  /* 67.2*log2(e) */
#define LN2 0.69314718056f

__device__ __forceinline__ unsigned short f2bf(float f) {
    unsigned int u = __float_as_uint(f);
    unsigned int r = (u + 0x7FFFu + ((u >> 16) & 1u)) >> 16;  // RNE
    return (unsigned short)r;
}

// Fragment-swizzled layout (uint4 units): fb[grp*256 + chunk*16 + row16]
//   grp = slot>>4, row16 = slot&15, chunk = 8-bf16 block (16B) in [0,16).
// MFMA frag load for K-block kc reads fb[grp*256 + kc*64 + lane].
// Rows stored label-sorted; same-label columns of any 16-row wave group are
// one contiguous range [lo, hi); tiles outside it use the 5-op negative path.

// ---------------- sort pipeline (parallel counting sort) ------------------------
// NOTE: no runtime API calls in kernel_launch (graph capture) — hist is zeroed
// by a kernel, not hipMemsetAsync. [R3 lesson: container failed with memset]
__global__ __launch_bounds__(512) void k_zero(int* __restrict__ hist) {
    hist[threadIdx.x] = 0;
}

__global__ __launch_bounds__(256) void k_hist(const int* __restrict__ labels,
                                              int* __restrict__ hist) {
    int i = blockIdx.x * 256 + threadIdx.x;
    atomicAdd(&hist[labels[i]], 1);
}

// 1 block, 512 threads: exclusive scan hist -> start (and base copy).
__global__ __launch_bounds__(512) void k_scan(const int* __restrict__ hist,
                                              int* __restrict__ start,
                                              int* __restrict__ base) {
    __shared__ int wsum[8];
    int t = threadIdx.x;
    int v = hist[t];
    int x = v;
#pragma unroll
    for (int m = 1; m < 64; m <<= 1) {
        int y = __shfl_up(x, m);
        if ((t & 63) >= m) x += y;
    }
    if ((t & 63) == 63) wsum[t >> 6] = x;
    __syncthreads();
    int w = t >> 6, woff = 0;
#pragma unroll
    for (int k = 0; k < 8; k++)
        if (k < w) woff += wsum[k];
    int excl = woff + x - v;  // exclusive prefix over classes
    start[t] = excl;
    base[t] = excl;
    if (t == 0) start[NCLS] = NN_;
}

__global__ __launch_bounds__(256) void k_scatter(const int* __restrict__ labels,
                                                 int* __restrict__ base,
                                                 int* __restrict__ srcrow,
                                                 int* __restrict__ plab) {
    int row = blockIdx.x * 256 + threadIdx.x;
    int l = labels[row];
    int p = atomicAdd(&base[l], 1);
    srcrow[p] = row;
    plab[p] = l;
}

// ---------------- kernel 1: L2-normalize rows -> bf16 (gather, coalesced store) -
__global__ __launch_bounds__(256) void k_norm(const float* __restrict__ x,
                                              const int* __restrict__ srcrow,
                                              unsigned short* __restrict__ ebf) {
    int t = threadIdx.x;
    int r16 = t >> 4;
    int g = t & 15;
    int slot = blockIdx.x * 16 + r16;
    int orig = srcrow[slot];  // 16 threads/row load same value (cache broadcast)
    const float4* xr = (const float4*)(x + (size_t)orig * DD_);
    float4 v0 = xr[g * 2];
    float4 v1 = xr[g * 2 + 1];
    float ss = v0.x * v0.x + v0.y * v0.y + v0.z * v0.z + v0.w * v0.w +
               v1.x * v1.x + v1.y * v1.y + v1.z * v1.z + v1.w * v1.w;
#pragma unroll
    for (int m = 1; m < 16; m <<= 1) ss += __shfl_xor(ss, m);
    float inv = 1.0f / fmaxf(sqrtf(ss), 1e-12f);
    float vs[8] = {v0.x, v0.y, v0.z, v0.w, v1.x, v1.y, v1.z, v1.w};
    unsigned int p[4];
#pragma unroll
    for (int k = 0; k < 4; k++) {
        unsigned short lo = f2bf(vs[2 * k] * inv);
        unsigned short hi = f2bf(vs[2 * k + 1] * inv);
        p[k] = (unsigned int)lo | ((unsigned int)hi << 16);
    }
    uint4 out = {p[0], p[1], p[2], p[3]};
    ((uint4*)ebf)[blockIdx.x * 256 + g * 16 + r16] = out;  // coalesced swizzled store
}

// ---------------- kernel 2: main sim + masked LSE pass --------------------------
// grid (NSPLIT=16, 64) = 1024 blocks -> 4 blocks/CU resident when VGPR <= 64.
// launch_bounds min-waves kept at 4 (128-VGPR cap): forcing 8 caused scratch
// spills (round 2: VGPR 32, 272MB scratch writes, 5.5x slower). [R2 lesson]
__global__ __launch_bounds__(512, 4) void k_main(const unsigned short* __restrict__ ebf,
                                                 const int* __restrict__ plab,
                                                 const int* __restrict__ start,
                                                 float* __restrict__ states) {
    const int lane = threadIdx.x & 63;
    const int wave = threadIdx.x >> 6;
    const int quad = lane >> 4;
    const int lcol = lane & 15;
    const int rowbase = blockIdx.y * 128 + wave * 16;
    const int jsplit = blockIdx.x;
    const int j0 = jsplit * JSPLIT;

    const uint4* fb = (const uint4*)ebf;

    U4 afr[4];
#pragma unroll
    for (int kc = 0; kc < 4; kc++) afr[kc].u = fb[(rowbase >> 4) * 256 + kc * 64 + lane];

    int il[4];
#pragma unroll
    for (int r = 0; r < 4; r++) il[r] = plab[rowbase + quad * 4 + r];

    // wave-uniform same-label column range [lo, hi)
    int labmin = __builtin_amdgcn_readfirstlane(plab[rowbase]);
    int labmax = __builtin_amdgcn_readfirstlane(plab[rowbase + 15]);
    int lo = __builtin_amdgcn_readfirstlane(start[labmin]);
    int hi = __builtin_amdgcn_readfirstlane(start[labmax + 1]);

    float S_an[4] = {0.f, 0.f, 0.f, 0.f};
    float m_p[4] = {-1e30f, -1e30f, -1e30f, -1e30f};  // log2 units
    float s_p[4] = {0.f, 0.f, 0.f, 0.f};
    float cnt[4] = {0.f, 0.f, 0.f, 0.f};  // same-label count (incl self)

    U4 b0[4], b1[4];
#pragma unroll
    for (int kc = 0; kc < 4; kc++) b0[kc].u = fb[(j0 >> 4) * 256 + kc * 64 + lane];
#pragma unroll
    for (int kc = 0; kc < 4; kc++) b1[kc].u = fb[((j0 + 16) >> 4) * 256 + kc * 64 + lane];

    const int NIT = JSPLIT / 32;
    for (int it = 0; it < NIT; ++it) {
        const int jt = j0 + it * 32;
        const int jp = (it + 1 < NIT) ? jt + 32 : j0;  // prefetch target (wrap ok)

        // ---- tile 0: columns jt..jt+15, fragments in b0 ----
        {
            f32x4 acc = {0.f, 0.f, 0.f, 0.f};
#pragma unroll
            for (int kc = 0; kc < 4; kc++)
                acc = __builtin_amdgcn_mfma_f32_16x16x32_bf16(afr[kc].h, b0[kc].h, acc, 0, 0, 0);
            // refill b0 now: load latency hides under the acc-dependent epilogue
#pragma unroll
            for (int kc = 0; kc < 4; kc++) b0[kc].u = fb[(jp >> 4) * 256 + kc * 64 + lane];
            if (jt < hi && jt + 16 > lo) {
                int jl = plab[jt + lcol];
                int j = jt + lcol;
#pragma unroll
                for (int r = 0; r < 4; r++) {
                    float s = acc[r];
                    int i = rowbase + quad * 4 + r;
                    bool same = (jl == il[r]);
                    float a = fmaxf(s + 0.4f, 0.0f);
                    float e = EXP2(fmaf(a * C1, s - 0.4f, -C2));
                    S_an[r] += same ? 0.0f : e;
                    cnt[r] += same ? 1.0f : 0.0f;
                    if (same && j != i) {
                        float al = fmaxf(1.4f - s, 0.0f) * (-C1);
                        float tp = al * (s - 0.6f);
                        float mn = fmaxf(m_p[r], tp);
                        s_p[r] = s_p[r] * EXP2(m_p[r] - mn) + EXP2(tp - mn);
                        m_p[r] = mn;
                    }
                }
            } else {
#pragma unroll
                for (int r = 0; r < 4; r++) {
                    float s = acc[r];
                    float a = fmaxf(s + 0.4f, 0.0f);
                    S_an[r] += EXP2(fmaf(a * C1, s - 0.4f, -C2));
                }
            }
        }

        // ---- tile 1: columns jt+16..jt+31, fragments in b1 ----
        {
            f32x4 acc = {0.f, 0.f, 0.f, 0.f};
#pragma unroll
            for (int kc = 0; kc < 4; kc++)
                acc = __builtin_amdgcn_mfma_f32_16x16x32_bf16(afr[kc].h, b1[kc].h, acc, 0, 0, 0);
#pragma unroll
            for (int kc = 0; kc < 4; kc++) b1[kc].u = fb[((jp + 16) >> 4) * 256 + kc * 64 + lane];
            const int jtt = jt + 16;
            if (jtt < hi && jtt + 16 > lo) {
                int jl = plab[jtt + lcol];
                int j = jtt + lcol;
#pragma unroll
                for (int r = 0; r < 4; r++) {
                    float s = acc[r];
                    int i = rowbase + quad * 4 + r;
                    bool same = (jl == il[r]);
                    float a = fmaxf(s + 0.4f, 0.0f);
                    float e = EXP2(fmaf(a * C1, s - 0.4f, -C2));
                    S_an[r] += same ? 0.0f : e;
                    cnt[r] += same ? 1.0f : 0.0f;
                    if (same && j != i) {
                        float al = fmaxf(1.4f - s, 0.0f) * (-C1);
                        float tp = al * (s - 0.6f);
                        float mn = fmaxf(m_p[r], tp);
                        s_p[r] = s_p[r] * EXP2(m_p[r] - mn) + EXP2(tp - mn);
                        m_p[r] = mn;
                    }
                }
            } else {
#pragma unroll
                for (int r = 0; r < 4; r++) {
                    float s = acc[r];
                    float a = fmaxf(s + 0.4f, 0.0f);
                    S_an[r] += EXP2(fmaf(a * C1, s - 0.4f, -C2));
                }
            }
        }
    }

#pragma unroll
    for (int r = 0; r < 4; r++) {
#pragma unroll
        for (int m = 1; m < 16; m <<= 1) {
            S_an[r] += __shfl_xor(S_an[r], m);
            cnt[r] += __shfl_xor(cnt[r], m);
            float m2 = __shfl_xor(m_p[r], m);
            float s2 = __shfl_xor(s_p[r], m);
            float mn = fmaxf(m_p[r], m2);
            s_p[r] = s_p[r] * EXP2(m_p[r] - mn) + s2 * EXP2(m2 - mn);
            m_p[r] = mn;
        }
    }
    if (lcol == 0) {
#pragma unroll
        for (int r = 0; r < 4; r++) {
            int i = rowbase + quad * 4 + r;
            float4 st = {m_p[r], s_p[r], S_an[r], cnt[r]};
            ((float4*)states)[(size_t)i * NSPLIT + jsplit] = st;
        }
    }
}

// ---------------- kernel 3: merge splits, per-row loss, per-wave partials -------
__global__ __launch_bounds__(256) void k_fin(const float* __restrict__ states,
                                             float* __restrict__ partials) {
    int i = blockIdx.x * 256 + threadIdx.x;
    float m_p = -1e30f, s_p = 0.f, S_an = 0.f, cnt = 0.f;
#pragma unroll
    for (int k = 0; k < NSPLIT; k++) {
        float4 st = ((const float4*)states)[(size_t)i * NSPLIT + k];
        S_an += st.z;
        cnt += st.w;
        float mn = fmaxf(m_p, st.x);
        s_p = s_p * EXP2(m_p - mn) + st.y * EXP2(st.x - mn);
        m_p = mn;
    }
    int np = (int)cnt - 1;
    int nn = NN_ - (int)cnt;
    float loss = 0.0f, v = 0.0f;
    if (np > 0 && nn > 0 && s_p > 0.f && S_an > 0.f) {
        float lse_p = LN2 * m_p + __logf(s_p);
        float lse_n = 67.2f + __logf(S_an);
        float z = lse_p + lse_n + __logf((float)np) + __logf((float)nn);
        loss = fmaxf(z, 0.0f) + log1pf(__expf(-fabsf(z)));  // stable softplus
        v = 1.0f;
    }
#pragma unroll
    for (int m = 1; m < 64; m <<= 1) {
        loss += __shfl_xor(loss, m);
        v += __shfl_xor(v, m);
    }
    if ((threadIdx.x & 63) == 0) {
        int w = (blockIdx.x << 2) | (threadIdx.x >> 6);
        partials[w * 2] = loss;
        partials[w * 2 + 1] = v;
    }
}

// ---------------- kernel 4: final reduce over 128 wave-partials -----------------
__global__ void k_div(const float* __restrict__ partials, float* __restrict__ out) {
    int t = threadIdx.x;  // 64 threads
    float loss = partials[t * 2] + partials[(t + 64) * 2];
    float v = partials[t * 2 + 1] + partials[(t + 64) * 2 + 1];
#pragma unroll
    for (int m = 1; m < 64; m <<= 1) {
        loss += __shfl_xor(loss, m);
        v += __shfl_xor(v, m);
    }
    if (t == 0) out[0] = loss / fmaxf(v, 1.0f);
}

// ---------------- launch --------------------------------------------------------
extern "C" void kernel_launch(void* const* d_in, const int* in_sizes, int n_in,
                              void* d_out, int out_size, void* d_ws, size_t ws_size,
                              hipStream_t stream) {
    const float* embeds = (const float*)d_in[0];
    const int* labels = (const int*)d_in[1];
    float* out = (float*)d_out;

    char* ws = (char*)d_ws;
    unsigned short* ebf = (unsigned short*)ws;  // 2,097,152 B
    float* states = (float*)(ws + 2097152);     // 8192*16*16 = 2,097,152 B
    float* partials = (float*)(ws + 4194304);   // 1,024 B
    int* srcrow = (int*)(ws + 4195328);         // 32,768 B
    int* plab = (int*)(ws + 4228096);           // 32,768 B
    int* start = (int*)(ws + 4260864);          // 2,052 B (513 ints)
    int* base = (int*)(ws + 4263168);           // 2,048 B
    int* hist = (int*)(ws + 4265216);           // 2,048 B

    k_zero<<<1, NCLS, 0, stream>>>(hist);
    k_hist<<<NN_ / 256, 256, 0, stream>>>(labels, hist);
    k_scan<<<1, NCLS, 0, stream>>>(hist, start, base);
    k_scatter<<<NN_ / 256, 256, 0, stream>>>(labels, base, srcrow, plab);
    k_norm<<<NN_ / 16, 256, 0, stream>>>(embeds, srcrow, ebf);
    k_main<<<dim3(NSPLIT, NN_ / 128), 512, 0, stream>>>(ebf, plab, start, states);
    k_fin<<<NN_ / 256, 256, 0, stream>>>(states, partials);
    k_div<<<1, 64, 0, stream>>>(partials, out);
}

// Round 5
// 105.683 us; speedup vs baseline: 2.7557x; 1.0599x over previous
//
#include <hip/hip_runtime.h>
#include <hip/hip_bf16.h>

#define NN_ 8192
#define DD_ 128
#define NCLS 512
#define NSPLIT 16
#define JSPLIT (NN_ / NSPLIT)  // 512

typedef short bf16x8 __attribute__((ext_vector_type(8)));
typedef float f32x4 __attribute__((ext_vector_type(4)));

union U4 { uint4 u; bf16x8 h; };

#if __has_builtin(__builtin_amdgcn_exp2f)
#define EXP2(x) __builtin_amdgcn_exp2f(x)
#else
#define EXP2(x) __expf((x) * 0.69314718056f)
#endif

#define C1 115.415603f  /* 80*log2(e) */
#define C2 96.9491065f  /* 67.2*log2(e) */
#define LN2 0.69314718056f

__device__ __forceinline__ unsigned short f2bf(float f) {
    unsigned int u = __float_as_uint(f);
    unsigned int r = (u + 0x7FFFu + ((u >> 16) & 1u)) >> 16;  // RNE
    return (unsigned short)r;
}

// Fragment-swizzled layout (uint4 units): fb[grp*256 + chunk*16 + row16]
//   grp = slot>>4, row16 = slot&15, chunk = 8-bf16 block (16B) in [0,16).
// MFMA frag load for K-block kc reads fb[grp*256 + kc*64 + lane] -> each
// 16-column group is 4KB CONTIGUOUS, so a 32-col tile is one 8KB memcpy.
// Rows stored label-sorted; same-label columns of any 16-row wave group are
// one contiguous range [lo, hi); tiles outside it use the 5-op negative path.
//
// R5: B-tiles staged in LDS once per block (8 waves shared the same columns but
// each pulled its own copy from L2 -> 1.07 GB/dispatch ~= 25 TB/s, ~72% of the
// L2 ceiling — that was the R4 bottleneck; occupancy/grid changes were null).

// ---------------- sort pipeline (parallel counting sort) ------------------------
// NOTE: no runtime API calls in kernel_launch (graph capture) — hist zeroed by
// a kernel, not hipMemsetAsync. [R3 lesson]
__global__ __launch_bounds__(512) void k_zero(int* __restrict__ hist) {
    hist[threadIdx.x] = 0;
}

__global__ __launch_bounds__(256) void k_hist(const int* __restrict__ labels,
                                              int* __restrict__ hist) {
    int i = blockIdx.x * 256 + threadIdx.x;
    atomicAdd(&hist[labels[i]], 1);
}

// 1 block, 512 threads: exclusive scan hist -> start (and base copy).
__global__ __launch_bounds__(512) void k_scan(const int* __restrict__ hist,
                                              int* __restrict__ start,
                                              int* __restrict__ base) {
    __shared__ int wsum[8];
    int t = threadIdx.x;
    int v = hist[t];
    int x = v;
#pragma unroll
    for (int m = 1; m < 64; m <<= 1) {
        int y = __shfl_up(x, m);
        if ((t & 63) >= m) x += y;
    }
    if ((t & 63) == 63) wsum[t >> 6] = x;
    __syncthreads();
    int w = t >> 6, woff = 0;
#pragma unroll
    for (int k = 0; k < 8; k++)
        if (k < w) woff += wsum[k];
    int excl = woff + x - v;  // exclusive prefix over classes
    start[t] = excl;
    base[t] = excl;
    if (t == 0) start[NCLS] = NN_;
}

__global__ __launch_bounds__(256) void k_scatter(const int* __restrict__ labels,
                                                 int* __restrict__ base,
                                                 int* __restrict__ srcrow,
                                                 int* __restrict__ plab) {
    int row = blockIdx.x * 256 + threadIdx.x;
    int l = labels[row];
    int p = atomicAdd(&base[l], 1);
    srcrow[p] = row;
    plab[p] = l;
}

// ---------------- kernel 1: L2-normalize rows -> bf16 (gather, coalesced store) -
__global__ __launch_bounds__(256) void k_norm(const float* __restrict__ x,
                                              const int* __restrict__ srcrow,
                                              unsigned short* __restrict__ ebf) {
    int t = threadIdx.x;
    int r16 = t >> 4;
    int g = t & 15;
    int slot = blockIdx.x * 16 + r16;
    int orig = srcrow[slot];  // 16 threads/row load same value (cache broadcast)
    const float4* xr = (const float4*)(x + (size_t)orig * DD_);
    float4 v0 = xr[g * 2];
    float4 v1 = xr[g * 2 + 1];
    float ss = v0.x * v0.x + v0.y * v0.y + v0.z * v0.z + v0.w * v0.w +
               v1.x * v1.x + v1.y * v1.y + v1.z * v1.z + v1.w * v1.w;
#pragma unroll
    for (int m = 1; m < 16; m <<= 1) ss += __shfl_xor(ss, m);
    float inv = 1.0f / fmaxf(sqrtf(ss), 1e-12f);
    float vs[8] = {v0.x, v0.y, v0.z, v0.w, v1.x, v1.y, v1.z, v1.w};
    unsigned int p[4];
#pragma unroll
    for (int k = 0; k < 4; k++) {
        unsigned short lo = f2bf(vs[2 * k] * inv);
        unsigned short hi = f2bf(vs[2 * k + 1] * inv);
        p[k] = (unsigned int)lo | ((unsigned int)hi << 16);
    }
    uint4 out = {p[0], p[1], p[2], p[3]};
    ((uint4*)ebf)[blockIdx.x * 256 + g * 16 + r16] = out;  // coalesced swizzled store
}

// ---------------- kernel 2: main sim + masked LSE pass --------------------------
// grid (NSPLIT=16, 64) = 1024 blocks, 512 threads (8 waves). All 8 waves of a
// block scan the same columns: B-tiles staged in LDS once per block (double-
// buffered 2x8KB), async-split (global load issued early, ds_write late).
// launch_bounds min-waves kept at 4: forcing 8 caused scratch spills. [R2]
__global__ __launch_bounds__(512, 4) void k_main(const unsigned short* __restrict__ ebf,
                                                 const int* __restrict__ plab,
                                                 const int* __restrict__ start,
                                                 float* __restrict__ states) {
    __shared__ uint4 bsh[1024];  // 2 buffers x 512 uint4 (8KB each)

    const int tid = threadIdx.x;
    const int lane = tid & 63;
    const int wave = tid >> 6;
    const int quad = lane >> 4;
    const int lcol = lane & 15;
    const int rowbase = blockIdx.y * 128 + wave * 16;
    const int jsplit = blockIdx.x;
    const int j0 = jsplit * JSPLIT;

    const uint4* fb = (const uint4*)ebf;

    U4 afr[4];
#pragma unroll
    for (int kc = 0; kc < 4; kc++) afr[kc].u = fb[(rowbase >> 4) * 256 + kc * 64 + lane];

    int il[4];
#pragma unroll
    for (int r = 0; r < 4; r++) il[r] = plab[rowbase + quad * 4 + r];

    // wave-uniform same-label column range [lo, hi)
    int labmin = __builtin_amdgcn_readfirstlane(plab[rowbase]);
    int labmax = __builtin_amdgcn_readfirstlane(plab[rowbase + 15]);
    int lo = __builtin_amdgcn_readfirstlane(start[labmin]);
    int hi = __builtin_amdgcn_readfirstlane(start[labmax + 1]);

    float S_an[4] = {0.f, 0.f, 0.f, 0.f};
    float m_p[4] = {-1e30f, -1e30f, -1e30f, -1e30f};  // log2 units
    float s_p[4] = {0.f, 0.f, 0.f, 0.f};
    float cnt[4] = {0.f, 0.f, 0.f, 0.f};  // same-label count (incl self)

    // prologue: stage tile 0 (cols j0..j0+31, 8KB contiguous) into buffer 0
    bsh[tid] = fb[(j0 >> 4) * 256 + tid];
    __syncthreads();

    const int NIT = JSPLIT / 32;
    for (int it = 0; it < NIT; ++it) {
        const int cur = it & 1;
        const int jt = j0 + it * 32;
        const bool has = (it + 1 < NIT);

        // async-split stage: issue the global load NOW (lands during compute)
        uint4 stg;
        if (has) stg = fb[((jt + 32) >> 4) * 256 + tid];

        const int bb = (cur << 9) + lane;  // uint4 index into bsh

        // ---- two 16-col subtiles from LDS buffer `cur` ----
#pragma unroll
        for (int c = 0; c < 2; c++) {
            U4 bf[4];
#pragma unroll
            for (int kc = 0; kc < 4; kc++) bf[kc].u = bsh[bb + c * 256 + kc * 64];
            f32x4 acc = {0.f, 0.f, 0.f, 0.f};
#pragma unroll
            for (int kc = 0; kc < 4; kc++)
                acc = __builtin_amdgcn_mfma_f32_16x16x32_bf16(afr[kc].h, bf[kc].h, acc, 0, 0, 0);
            const int jc = jt + c * 16;
            if (jc < hi && jc + 16 > lo) {
                int jl = plab[jc + lcol];
                int j = jc + lcol;
#pragma unroll
                for (int r = 0; r < 4; r++) {
                    float s = acc[r];
                    int i = rowbase + quad * 4 + r;
                    bool same = (jl == il[r]);
                    float a = fmaxf(s + 0.4f, 0.0f);
                    float e = EXP2(fmaf(a * C1, s - 0.4f, -C2));
                    S_an[r] += same ? 0.0f : e;
                    cnt[r] += same ? 1.0f : 0.0f;
                    if (same && j != i) {
                        float al = fmaxf(1.4f - s, 0.0f) * (-C1);
                        float tp = al * (s - 0.6f);
                        float mn = fmaxf(m_p[r], tp);
                        s_p[r] = s_p[r] * EXP2(m_p[r] - mn) + EXP2(tp - mn);
                        m_p[r] = mn;
                    }
                }
            } else {
#pragma unroll
                for (int r = 0; r < 4; r++) {
                    float s = acc[r];
                    float a = fmaxf(s + 0.4f, 0.0f);
                    S_an[r] += EXP2(fmaf(a * C1, s - 0.4f, -C2));
                }
            }
        }

        // late half of the stage: write next tile into the other buffer.
        // Reads of that buffer finished before the PREVIOUS barrier -> safe.
        if (has) bsh[(cur ^ 1) * 512 + tid] = stg;
        __syncthreads();
    }

#pragma unroll
    for (int r = 0; r < 4; r++) {
#pragma unroll
        for (int m = 1; m < 16; m <<= 1) {
            S_an[r] += __shfl_xor(S_an[r], m);
            cnt[r] += __shfl_xor(cnt[r], m);
            float m2 = __shfl_xor(m_p[r], m);
            float s2 = __shfl_xor(s_p[r], m);
            float mn = fmaxf(m_p[r], m2);
            s_p[r] = s_p[r] * EXP2(m_p[r] - mn) + s2 * EXP2(m2 - mn);
            m_p[r] = mn;
        }
    }
    if (lcol == 0) {
#pragma unroll
        for (int r = 0; r < 4; r++) {
            int i = rowbase + quad * 4 + r;
            float4 st = {m_p[r], s_p[r], S_an[r], cnt[r]};
            ((float4*)states)[(size_t)i * NSPLIT + jsplit] = st;
        }
    }
}

// ---------------- kernel 3: merge splits, per-row loss, per-wave partials -------
__global__ __launch_bounds__(256) void k_fin(const float* __restrict__ states,
                                             float* __restrict__ partials) {
    int i = blockIdx.x * 256 + threadIdx.x;
    float m_p = -1e30f, s_p = 0.f, S_an = 0.f, cnt = 0.f;
#pragma unroll
    for (int k = 0; k < NSPLIT; k++) {
        float4 st = ((const float4*)states)[(size_t)i * NSPLIT + k];
        S_an += st.z;
        cnt += st.w;
        float mn = fmaxf(m_p, st.x);
        s_p = s_p * EXP2(m_p - mn) + st.y * EXP2(st.x - mn);
        m_p = mn;
    }
    int np = (int)cnt - 1;
    int nn = NN_ - (int)cnt;
    float loss = 0.0f, v = 0.0f;
    if (np > 0 && nn > 0 && s_p > 0.f && S_an > 0.f) {
        float lse_p = LN2 * m_p + __logf(s_p);
        float lse_n = 67.2f + __logf(S_an);
        float z = lse_p + lse_n + __logf((float)np) + __logf((float)nn);
        loss = fmaxf(z, 0.0f) + log1pf(__expf(-fabsf(z)));  // stable softplus
        v = 1.0f;
    }
#pragma unroll
    for (int m = 1; m < 64; m <<= 1) {
        loss += __shfl_xor(loss, m);
        v += __shfl_xor(v, m);
    }
    if ((threadIdx.x & 63) == 0) {
        int w = (blockIdx.x << 2) | (threadIdx.x >> 6);
        partials[w * 2] = loss;
        partials[w * 2 + 1] = v;
    }
}

// ---------------- kernel 4: final reduce over 128 wave-partials -----------------
__global__ void k_div(const float* __restrict__ partials, float* __restrict__ out) {
    int t = threadIdx.x;  // 64 threads
    float loss = partials[t * 2] + partials[(t + 64) * 2];
    float v = partials[t * 2 + 1] + partials[(t + 64) * 2 + 1];
#pragma unroll
    for (int m = 1; m < 64; m <<= 1) {
        loss += __shfl_xor(loss, m);
        v += __shfl_xor(v, m);
    }
    if (t == 0) out[0] = loss / fmaxf(v, 1.0f);
}

// ---------------- launch --------------------------------------------------------
extern "C" void kernel_launch(void* const* d_in, const int* in_sizes, int n_in,
                              void* d_out, int out_size, void* d_ws, size_t ws_size,
                              hipStream_t stream) {
    const float* embeds = (const float*)d_in[0];
    const int* labels = (const int*)d_in[1];
    float* out = (float*)d_out;

    char* ws = (char*)d_ws;
    unsigned short* ebf = (unsigned short*)ws;  // 2,097,152 B
    float* states = (float*)(ws + 2097152);     // 8192*16*16 = 2,097,152 B
    float* partials = (float*)(ws + 4194304);   // 1,024 B
    int* srcrow = (int*)(ws + 4195328);         // 32,768 B
    int* plab = (int*)(ws + 4228096);           // 32,768 B
    int* start = (int*)(ws + 4260864);          // 2,052 B (513 ints)
    int* base = (int*)(ws + 4263168);           // 2,048 B
    int* hist = (int*)(ws + 4265216);           // 2,048 B

    k_zero<<<1, NCLS, 0, stream>>>(hist);
    k_hist<<<NN_ / 256, 256, 0, stream>>>(labels, hist);
    k_scan<<<1, NCLS, 0, stream>>>(hist, start, base);
    k_scatter<<<NN_ / 256, 256, 0, stream>>>(labels, base, srcrow, plab);
    k_norm<<<NN_ / 16, 256, 0, stream>>>(embeds, srcrow, ebf);
    k_main<<<dim3(NSPLIT, NN_ / 128), 512, 0, stream>>>(ebf, plab, start, states);
    k_fin<<<NN_ / 256, 256, 0, stream>>>(states, partials);
    k_div<<<1, 64, 0, stream>>>(partials, out);
}